// Round 3
// baseline (659.200 us; speedup 1.0000x reference)
//
#include <hip/hip_runtime.h>
#include <math.h>

#define DIM 128
#define NEG_K 20
#define NBUCKET 4096

typedef unsigned int u32;
typedef unsigned long long u64;

// Numerically stable log(sigmoid(x)) = min(x,0) - log1p(exp(-|x|))
__device__ __forceinline__ float log_sigmoid(float x) {
    float m = fminf(x, 0.0f);
    return m - log1pf(__expf(-fabsf(x)));
}

// ---------------------------------------------------------------------------
// Pipeline: the original kernel issues 360K random 512B gathers over a 512MB
// table with cold caches (the harness's 2GB ws-poison fill evicts everything
// every iteration) -> latency/TLB/DRAM-row-bound at ~0.8 TB/s, insensitive to
// instruction economy (proven by rounds 0-2). Fix the ACCESS ORDER instead:
//   k_vgather : stage v_b = emb[target[b]] into dense vbuf (8MB)
//   k_hist/k_scan/k_scatter : bucket 344K (row,b,k) tasks by row>>8
//   k_dots    : gather emb[row] in ascending-bucket order (quasi-sequential:
//               DRAM row-buffer + TLB locality, dup rows hit L2),
//               dot against vbuf[b] (L2/L3-resident), write res[k*B+b]
//   k_loss    : per-b fixed-order sum of 20 neg scores + pos -> log-sigmoids
//   reduce    : final mean
// All res slots written exactly once -> deterministic output.
// ---------------------------------------------------------------------------

__global__ __launch_bounds__(256) void k_zero_hist(u32* __restrict__ hist) {
    const int i = blockIdx.x * 256 + threadIdx.x;
    if (i < NBUCKET) hist[i] = 0u;
}

// One wave per b: stage the 512B target row into vbuf (coalesced write).
__global__ __launch_bounds__(256) void k_vgather(const int* __restrict__ target,
                                                 const float* __restrict__ emb,
                                                 float* __restrict__ vbuf, int B) {
    const int lane = threadIdx.x & 63;
    const int b = (blockIdx.x * 256 + threadIdx.x) >> 6;
    if (b >= B) return;
    const int tgt = __builtin_amdgcn_readfirstlane(target[b]);
    ((float2*)(vbuf + (size_t)b * DIM))[lane] =
        ((const float2*)(emb + (size_t)tgt * DIM))[lane];
}

__device__ __forceinline__ u32 task_row(const int* context, const int* neg,
                                        int b, int k) {
    return (u32)((k < NEG_K) ? neg[b * NEG_K + k] : context[b]);
}

__global__ __launch_bounds__(256) void k_hist(const int* __restrict__ context,
                                              const int* __restrict__ neg,
                                              u32* __restrict__ hist, int B) {
    const int t = blockIdx.x * 256 + threadIdx.x;
    if (t >= B * 21) return;
    const int b = t / 21, k = t - b * 21;          // const-div -> magic mul
    const u32 row = task_row(context, neg, b, k);
    atomicAdd(&hist[(row >> 8) & (NBUCKET - 1)], 1u);
}

// Exclusive scan of 4096 bins, one block of 256 threads (16 bins each).
__global__ __launch_bounds__(256) void k_scan(const u32* __restrict__ hist,
                                              u32* __restrict__ offs) {
    __shared__ u32 s[256];
    const int t = threadIdx.x;
    u32 loc[16];
    u32 sum = 0;
    #pragma unroll
    for (int i = 0; i < 16; ++i) { loc[i] = hist[t * 16 + i]; sum += loc[i]; }
    s[t] = sum;
    __syncthreads();
    for (int off = 1; off < 256; off <<= 1) {
        const u32 v = (t >= off) ? s[t - off] : 0u;
        __syncthreads();
        s[t] += v;
        __syncthreads();
    }
    u32 run = s[t] - sum;                          // exclusive prefix of chunk
    #pragma unroll
    for (int i = 0; i < 16; ++i) { offs[t * 16 + i] = run; run += loc[i]; }
}

__global__ __launch_bounds__(256) void k_scatter(const int* __restrict__ context,
                                                 const int* __restrict__ neg,
                                                 u32* __restrict__ offs,
                                                 u64* __restrict__ tasks, int B) {
    const int t = blockIdx.x * 256 + threadIdx.x;
    if (t >= B * 21) return;
    const int b = t / 21, k = t - b * 21;
    const u32 row = task_row(context, neg, b, k);
    const u32 p = atomicAdd(&offs[(row >> 8) & (NBUCKET - 1)], 1u);
    tasks[p] = ((u64)row << 32) | ((u32)b << 5) | (u32)k;
}

// One wave per task-group of 8 consecutive (sorted) tasks; lane holds float2.
// Row gathers are ascending -> near-streaming DRAM behavior; vbuf reads hit
// L2/L3 (8MB dense buffer). All 8 iterations independent -> compiler pipelines
// the loads (16 outstanding 512B reads per wave).
#define TPW 8
__global__ __launch_bounds__(256) void k_dots(const u64* __restrict__ tasks,
                                              const float* __restrict__ emb,
                                              const float* __restrict__ vbuf,
                                              float* __restrict__ res,
                                              int B, int NT) {
    const int lane = threadIdx.x & 63;
    int base = ((blockIdx.x * 256 + threadIdx.x) >> 6) * TPW;
    base = __builtin_amdgcn_readfirstlane(base);   // SGPR base -> s_load tasks
    #pragma unroll
    for (int i = 0; i < TPW; ++i) {
        const int ti = base + i;
        if (ti < NT) {
            const u64 tv = tasks[ti];
            const u32 row = (u32)(tv >> 32);
            const u32 bk  = (u32)tv;
            const u32 b = bk >> 5, k = bk & 31u;
            const float2 e  = ((const float2*)(emb  + (size_t)row * DIM))[lane];
            const float2 vv = ((const float2*)(vbuf + (size_t)b   * DIM))[lane];
            float d = e.x * vv.x + e.y * vv.y;
            #pragma unroll
            for (int off = 32; off; off >>= 1) d += __shfl_xor(d, off);
            if (lane == 0) res[(int)k * B + (int)b] = d;
        }
    }
}

// Per-b loss terms; fixed k-order sum (deterministic); one partial per block.
__global__ __launch_bounds__(256) void k_loss(const float* __restrict__ res,
                                              float* __restrict__ partials,
                                              int B) {
    const int b = blockIdx.x * 256 + threadIdx.x;
    float term = 0.0f;
    if (b < B) {
        float ng = 0.0f;
        #pragma unroll
        for (int k = 0; k < NEG_K; ++k) ng += res[k * B + b];  // coalesced
        const float pos = res[NEG_K * B + b];
        term = log_sigmoid(pos) + log_sigmoid(-ng);
    }
    #pragma unroll
    for (int off = 32; off; off >>= 1) term += __shfl_xor(term, off);
    __shared__ float wsum[4];
    if ((threadIdx.x & 63) == 0) wsum[threadIdx.x >> 6] = term;
    __syncthreads();
    if (threadIdx.x == 0)
        partials[blockIdx.x] = wsum[0] + wsum[1] + wsum[2] + wsum[3];
}

// Final reduction of per-block partials; writes the loss.
__global__ __launch_bounds__(256) void sgns_reduce_kernel(
    const float* __restrict__ partials, float* __restrict__ out,
    int n, float invB)
{
    float s = 0.0f;
    for (int i = threadIdx.x; i < n; i += 256) s += partials[i];
    #pragma unroll
    for (int off = 32; off; off >>= 1) s += __shfl_xor(s, off);

    __shared__ float wsum[4];
    const int lane = threadIdx.x & 63;
    if (lane == 0) wsum[threadIdx.x >> 6] = s;
    __syncthreads();
    if (threadIdx.x == 0)
        out[0] = -(wsum[0] + wsum[1] + wsum[2] + wsum[3]) * invB;
}

extern "C" void kernel_launch(void* const* d_in, const int* in_sizes, int n_in,
                              void* d_out, int out_size, void* d_ws, size_t ws_size,
                              hipStream_t stream) {
    const int*   target  = (const int*)d_in[0];
    const int*   context = (const int*)d_in[1];
    const int*   neg     = (const int*)d_in[2];
    const float* emb     = (const float*)d_in[3];
    float* out = (float*)d_out;
    const int B  = in_sizes[0];
    const int NT = B * 21;               // 20 neg + 1 context task per element

    // Workspace carve-up (runtime-sized, 256B aligned).
    char* ws = (char*)d_ws;
    float* partials = (float*)(ws + 0);                         // 16 KB
    u32*   hist     = (u32*)(ws + 16384);                       // 16 KB
    u32*   offs     = (u32*)(ws + 32768);                       // 16 KB
    size_t off_tasks = 65536;
    size_t off_res   = (off_tasks + (size_t)NT * 8 + 255) & ~(size_t)255;
    size_t off_vbuf  = (off_res + (size_t)(NEG_K + 1) * B * 4 + 255) & ~(size_t)255;
    u64*   tasks = (u64*)(ws + off_tasks);
    float* res   = (float*)(ws + off_res);
    float* vbuf  = (float*)(ws + off_vbuf);

    k_zero_hist<<<(NBUCKET + 255) / 256, 256, 0, stream>>>(hist);
    k_vgather<<<((size_t)B * 64 + 255) / 256, 256, 0, stream>>>(target, emb, vbuf, B);
    k_hist<<<(NT + 255) / 256, 256, 0, stream>>>(context, neg, hist, B);
    k_scan<<<1, 256, 0, stream>>>(hist, offs);
    k_scatter<<<(NT + 255) / 256, 256, 0, stream>>>(context, neg, offs, tasks, B);

    const int nwaves = (NT + TPW - 1) / TPW;
    k_dots<<<((size_t)nwaves * 64 + 255) / 256, 256, 0, stream>>>(
        tasks, emb, vbuf, res, B, NT);

    const int lblocks = (B + 255) / 256;
    k_loss<<<lblocks, 256, 0, stream>>>(res, partials, B);
    sgns_reduce_kernel<<<1, 256, 0, stream>>>(partials, out, lblocks,
                                              1.0f / (float)B);
}